// Round 3
// baseline (862.200 us; speedup 1.0000x reference)
//
#include <hip/hip_runtime.h>

typedef unsigned short u16;
typedef unsigned int u32;
using short8  = __attribute__((ext_vector_type(8))) short;
using floatx4 = __attribute__((ext_vector_type(4))) float;

#define NB 32
#define SEQ 1024
#define EMB 512
#define NH 8
#define HD 64
#define NLAYER 2
#define M_ROWS (NB * SEQ)   // 32768

__device__ __forceinline__ float bf2f(u16 u) {
  union { u32 i; float f; } v; v.i = ((u32)u) << 16; return v.f;
}
__device__ __forceinline__ u16 f2bf(float f) {
  union { float f; u32 i; } v; v.f = f;
  u32 r = v.i + 0x7fffu + ((v.i >> 16) & 1u);
  return (u16)(r >> 16);
}

// ---------------- weight pre-transpose + fp32->bf16: W[K,N] -> Bt[N,K] ------
// WtQKV: [L][1536][512]  (n in [0,512)=Q, [512,1024)=K, [1024,1536)=V)
// WtO:   [L][512][512]
__global__ void prep_weights(const float* __restrict__ Wq, const float* __restrict__ Wk,
                             const float* __restrict__ Wv, const float* __restrict__ Wo,
                             u16* __restrict__ WtQKV, u16* __restrict__ WtO) {
  int idx = blockIdx.x * 256 + threadIdx.x;  // total 2*1536*512 + 2*512*512 = 2097152
  const int QKV_TOT = NLAYER * 3 * EMB * EMB;
  if (idx < QKV_TOT) {
    int l = idx / (3 * EMB * EMB);
    int rem = idx % (3 * EMB * EMB);
    int n = rem / EMB, kk = rem % EMB;
    int w = n >> 9, e = n & 511;
    const float* src = (w == 0) ? Wq : (w == 1) ? Wk : Wv;
    WtQKV[idx] = f2bf(src[((size_t)l * EMB + kk) * EMB + e]);
  } else {
    int j = idx - QKV_TOT;
    int l = j / (EMB * EMB);
    int rem = j % (EMB * EMB);
    int n = rem / EMB, kk = rem % EMB;
    WtO[j] = f2bf(Wo[((size_t)l * EMB + kk) * EMB + n]);
  }
}

// ---------------- embedding + positional encoding (fp32 in, bf16 out) -------
__global__ void embed_pe(const int* __restrict__ inp, const float* __restrict__ table,
                         u16* __restrict__ x) {
  int row = blockIdx.x;            // 0..32767 = b*1024+s
  int tok = inp[row];
  int s = row & (SEQ - 1);
  const float negln = -9.210340371976184f / (float)EMB;  // -ln(10000)/E
  for (int e = threadIdx.x; e < EMB; e += blockDim.x) {
    float val = table[(size_t)tok * EMB + e];
    int i = e >> 1;
    float dt = expf((float)(2 * i) * negln);
    float ang = (float)s * dt;
    float pe = (e & 1) ? cosf(ang) : sinf(ang);
    x[(size_t)row * EMB + e] = f2bf(val + pe);
  }
}

// ---------------- GEMM: C[M,N] = A[M,K] @ Bt[N,K]^T + bias, with epilogues ----
// mode 0: N=1536, scatter to q/k/v [B,H,S,D] head-major, bias per section
// mode 1: N=512,  x = x + relu(C + bias)   (in place on out0 == resid)
#define BK 32
#define LSTR 40   // 32 + 8 pad (2-way bank aliasing only -> free)

__global__ __launch_bounds__(256) void gemm_bt(
    const u16* __restrict__ A, const u16* __restrict__ Bt, int K, int mode,
    const float* bias0, const float* bias1, const float* bias2,
    u16* out0, u16* out1, u16* out2, const u16* resid, int Nstride) {
  __shared__ u16 sA[128][LSTR];
  __shared__ u16 sB[128][LSTR];
  int tid = threadIdx.x;
  int wave = tid >> 6, lane = tid & 63;
  int quad = lane >> 4, l16 = lane & 15;
  int wm = wave >> 1, wn = wave & 1;
  int bn0 = blockIdx.x * 128, bm0 = blockIdx.y * 128;

  floatx4 acc[4][4];
#pragma unroll
  for (int i = 0; i < 4; ++i)
#pragma unroll
    for (int j = 0; j < 4; ++j) acc[i][j] = (floatx4){0.f, 0.f, 0.f, 0.f};

  for (int k0 = 0; k0 < K; k0 += BK) {
#pragma unroll
    for (int i = 0; i < 2; ++i) {
      int cc = tid + i * 256;          // 512 chunks of 8 elems per tile
      int row = cc >> 2, cg = cc & 3;
      *(uint4*)&sA[row][cg * 8] = *(const uint4*)&A[(size_t)(bm0 + row) * K + k0 + cg * 8];
      *(uint4*)&sB[row][cg * 8] = *(const uint4*)&Bt[(size_t)(bn0 + row) * K + k0 + cg * 8];
    }
    __syncthreads();
    short8 af[4], bfr[4];
#pragma unroll
    for (int mi = 0; mi < 4; ++mi)
      af[mi] = *(const short8*)&sA[wm * 64 + mi * 16 + l16][quad * 8];
#pragma unroll
    for (int ni = 0; ni < 4; ++ni)
      bfr[ni] = *(const short8*)&sB[wn * 64 + ni * 16 + l16][quad * 8];
#pragma unroll
    for (int mi = 0; mi < 4; ++mi)
#pragma unroll
      for (int ni = 0; ni < 4; ++ni)
        acc[mi][ni] = __builtin_amdgcn_mfma_f32_16x16x32_bf16(af[mi], bfr[ni], acc[mi][ni], 0, 0, 0);
    __syncthreads();
  }

#pragma unroll
  for (int mi = 0; mi < 4; ++mi) {
#pragma unroll
    for (int ni = 0; ni < 4; ++ni) {
#pragma unroll
      for (int r = 0; r < 4; ++r) {
        int m = bm0 + wm * 64 + mi * 16 + quad * 4 + r;   // C/D: row = quad*4+reg
        int n = bn0 + wn * 64 + ni * 16 + l16;            // C/D: col = lane&15
        float v = acc[mi][ni][r];
        if (mode == 0) {
          int w = n >> 9, e = n & 511;
          int h = e >> 6, d = e & 63;
          const float* bptr = (w == 0) ? bias0 : (w == 1) ? bias1 : bias2;
          v += bptr[e];
          u16* optr = (w == 0) ? out0 : (w == 1) ? out1 : out2;
          int b = m >> 10, sid = m & 1023;
          optr[((size_t)(b * NH + h) * SEQ + sid) * HD + d] = f2bf(v);
        } else {
          v += bias0[n];
          v = fmaxf(v, 0.f);
          v += bf2f(resid[(size_t)m * Nstride + n]);
          out0[(size_t)m * Nstride + n] = f2bf(v);
        }
      }
    }
  }
}

// ---------------- flash attention, causal, one block per (b*h, qtile) -------
__global__ __launch_bounds__(256) void attn_kernel(
    const u16* __restrict__ q, const u16* __restrict__ k, const u16* __restrict__ v,
    u16* __restrict__ o) {
  int bh = blockIdx.x;     // 0..255
  int qt = blockIdx.y;     // 0..15
  int b = bh >> 3, h = bh & 7;
  int q0 = qt * 64;
  __shared__ u16 sQ[64][72], sK[64][72], sVt[64][72], sP[64][72];
  int tid = threadIdx.x, wave = tid >> 6, lane = tid & 63;
  int quad = lane >> 4, l16 = lane & 15;

  // stage Q tile [64 q][64 d]
#pragma unroll
  for (int i = 0; i < 2; ++i) {
    int cc = tid + i * 256;
    int row = cc >> 3, cg = cc & 7;
    *(uint4*)&sQ[row][cg * 8] = *(const uint4*)&q[((size_t)bh * SEQ + q0 + row) * HD + cg * 8];
  }

  floatx4 acco[4];
#pragma unroll
  for (int i = 0; i < 4; ++i) acco[i] = (floatx4){0.f, 0.f, 0.f, 0.f};
  float mrow[4], lrow[4];
#pragma unroll
  for (int r = 0; r < 4; ++r) { mrow[r] = -INFINITY; lrow[r] = 0.f; }

  for (int kt = 0; kt <= qt; ++kt) {
    int k0 = kt * 64;
    __syncthreads();   // protect sK/sVt reuse (and sQ visibility at kt=0)
#pragma unroll
    for (int i = 0; i < 2; ++i) {
      int cc = tid + i * 256;
      int row = cc >> 3, cg = cc & 7;
      *(uint4*)&sK[row][cg * 8] = *(const uint4*)&k[((size_t)bh * SEQ + k0 + row) * HD + cg * 8];
      union { uint4 vv; u16 s[8]; } tmp;
      tmp.vv = *(const uint4*)&v[((size_t)bh * SEQ + k0 + row) * HD + cg * 8];
#pragma unroll
      for (int j = 0; j < 8; ++j) sVt[cg * 8 + j][row] = tmp.s[j];  // V^T: [d][key]
    }
    __syncthreads();

    // S = Q @ K^T * 1/8 ; wave handles 16 q-rows x 64 keys
    floatx4 accs[4];
#pragma unroll
    for (int i = 0; i < 4; ++i) accs[i] = (floatx4){0.f, 0.f, 0.f, 0.f};
#pragma unroll
    for (int cst = 0; cst < 2; ++cst) {
      short8 aq = *(const short8*)&sQ[wave * 16 + l16][cst * 32 + quad * 8];
#pragma unroll
      for (int nt = 0; nt < 4; ++nt) {
        short8 bk_ = *(const short8*)&sK[nt * 16 + l16][cst * 32 + quad * 8];
        accs[nt] = __builtin_amdgcn_mfma_f32_16x16x32_bf16(aq, bk_, accs[nt], 0, 0, 0);
      }
    }

    // online softmax (rows m = wave*16 + quad*4 + r, cols key = k0 + nt*16 + l16)
    int qg_base = q0 + wave * 16 + quad * 4;
    float pv[4][4];
#pragma unroll
    for (int r = 0; r < 4; ++r) {
      float mx = -INFINITY;
#pragma unroll
      for (int nt = 0; nt < 4; ++nt) {
        float s = accs[nt][r] * 0.125f;
        int kg = k0 + nt * 16 + l16;
        if (kg > qg_base + r) s = -INFINITY;   // causal mask (ref's -1e9 -> prob 0)
        pv[nt][r] = s;
        mx = fmaxf(mx, s);
      }
#pragma unroll
      for (int sh = 1; sh < 16; sh <<= 1) mx = fmaxf(mx, __shfl_xor(mx, sh, 64));
      float mn = fmaxf(mrow[r], mx);
      float alpha = __expf(mrow[r] - mn);
      float sum = 0.f;
#pragma unroll
      for (int nt = 0; nt < 4; ++nt) {
        float p = __expf(pv[nt][r] - mn);
        pv[nt][r] = p;
        sum += p;
      }
#pragma unroll
      for (int sh = 1; sh < 16; sh <<= 1) sum += __shfl_xor(sum, sh, 64);
      lrow[r] = lrow[r] * alpha + sum;
      mrow[r] = mn;
#pragma unroll
      for (int dt = 0; dt < 4; ++dt) acco[dt][r] *= alpha;
    }

    // P (C-layout) -> LDS -> A-layout for PV
#pragma unroll
    for (int nt = 0; nt < 4; ++nt)
#pragma unroll
      for (int r = 0; r < 4; ++r)
        sP[wave * 16 + quad * 4 + r][nt * 16 + l16] = f2bf(pv[nt][r]);
    __syncthreads();

#pragma unroll
    for (int cst = 0; cst < 2; ++cst) {
      short8 ap = *(const short8*)&sP[wave * 16 + l16][cst * 32 + quad * 8];
#pragma unroll
      for (int dt = 0; dt < 4; ++dt) {
        short8 bv_ = *(const short8*)&sVt[dt * 16 + l16][cst * 32 + quad * 8];
        acco[dt] = __builtin_amdgcn_mfma_f32_16x16x32_bf16(ap, bv_, acco[dt], 0, 0, 0);
      }
    }
  }

  // normalize + write [B,S,E]
#pragma unroll
  for (int dt = 0; dt < 4; ++dt)
#pragma unroll
    for (int r = 0; r < 4; ++r) {
      float ov = acco[dt][r] / lrow[r];
      int srow = q0 + wave * 16 + quad * 4 + r;
      int col = h * HD + dt * 16 + l16;
      o[((size_t)b * SEQ + srow) * EMB + col] = f2bf(ov);
    }
}

// ---------------- output head: out[m] = x[m,:] . W_out + b_out (fp32 out) ---
__global__ __launch_bounds__(256) void out_proj(const u16* __restrict__ x,
                                                const float* __restrict__ wout,
                                                const float* __restrict__ bout,
                                                float* __restrict__ out) {
  int wave = threadIdx.x >> 6, lane = threadIdx.x & 63;
  int m = blockIdx.x * 4 + wave;
  union { uint4 vv; u16 s[8]; } xv;
  xv.vv = *(const uint4*)&x[(size_t)m * EMB + lane * 8];
  float4 w0 = *(const float4*)&wout[lane * 8];
  float4 w1 = *(const float4*)&wout[lane * 8 + 4];
  float wv[8] = {w0.x, w0.y, w0.z, w0.w, w1.x, w1.y, w1.z, w1.w};
  float s = 0.f;
#pragma unroll
  for (int j = 0; j < 8; ++j) s += bf2f(xv.s[j]) * wv[j];
#pragma unroll
  for (int sh = 1; sh < 64; sh <<= 1) s += __shfl_xor(s, sh, 64);
  if (lane == 0) out[m] = s + bout[0];
}

extern "C" void kernel_launch(void* const* d_in, const int* in_sizes, int n_in,
                              void* d_out, int out_size, void* d_ws, size_t ws_size,
                              hipStream_t stream) {
  const int*   inp   = (const int*)d_in[0];
  const float* table = (const float*)d_in[1];
  const float* Wq    = (const float*)d_in[2];
  const float* bq    = (const float*)d_in[3];
  const float* Wk    = (const float*)d_in[4];
  const float* bk    = (const float*)d_in[5];
  const float* Wv    = (const float*)d_in[6];
  const float* bv    = (const float*)d_in[7];
  const float* Wo    = (const float*)d_in[8];
  const float* bo    = (const float*)d_in[9];
  const float* Wout  = (const float*)d_in[10];
  const float* bout  = (const float*)d_in[11];
  float* outp = (float*)d_out;

  char* ws = (char*)d_ws;
  const size_t SZ = (size_t)M_ROWS * EMB * 2;  // 32 MB
  u16* x      = (u16*)(ws);
  u16* qb     = (u16*)(ws + SZ);
  u16* kb     = (u16*)(ws + 2 * SZ);
  u16* vb     = (u16*)(ws + 3 * SZ);
  u16* attn_b = (u16*)(ws + 4 * SZ);
  u16* WtQKV  = (u16*)(ws + 5 * SZ);
  u16* WtO    = (u16*)(ws + 5 * SZ + (size_t)NLAYER * 3 * EMB * EMB * 2);

  prep_weights<<<8192, 256, 0, stream>>>(Wq, Wk, Wv, Wo, WtQKV, WtO);
  embed_pe<<<M_ROWS, 256, 0, stream>>>(inp, table, x);

  for (int l = 0; l < NLAYER; ++l) {
    gemm_bt<<<dim3(12, 256), 256, 0, stream>>>(
        x, WtQKV + (size_t)l * 3 * EMB * EMB, EMB, /*mode=*/0,
        bq + l * EMB, bk + l * EMB, bv + l * EMB, qb, kb, vb, nullptr, 0);
    attn_kernel<<<dim3(256, 16), 256, 0, stream>>>(qb, kb, vb, attn_b);
    gemm_bt<<<dim3(4, 256), 256, 0, stream>>>(
        attn_b, WtO + (size_t)l * EMB * EMB, EMB, /*mode=*/1,
        bo + l * EMB, nullptr, nullptr, x, nullptr, nullptr, x, EMB);
  }
  out_proj<<<8192, 256, 0, stream>>>(x, Wout, bout, outp);
}

// Round 4
// 821.326 us; speedup vs baseline: 1.0498x; 1.0498x over previous
//
#include <hip/hip_runtime.h>

typedef unsigned short u16;
typedef unsigned int u32;
using short8  = __attribute__((ext_vector_type(8))) short;
using floatx4 = __attribute__((ext_vector_type(4))) float;

#define NB 32
#define SEQ 1024
#define EMB 512
#define NH 8
#define HD 64
#define NLAYER 2
#define M_ROWS (NB * SEQ)   // 32768

__device__ __forceinline__ float bf2f(u16 u) {
  union { u32 i; float f; } v; v.i = ((u32)u) << 16; return v.f;
}
__device__ __forceinline__ u16 f2bf(float f) {
  union { float f; u32 i; } v; v.f = f;
  u32 r = v.i + 0x7fffu + ((v.i >> 16) & 1u);
  return (u16)(r >> 16);
}

// async global->LDS, 16B per lane. LDS dest = wave-uniform base + lane*16.
typedef __attribute__((address_space(3))) unsigned int lds_u32_t;
typedef __attribute__((address_space(1))) const unsigned int gbl_u32_t;
__device__ __forceinline__ void gload16(void* lds, const void* g) {
  gbl_u32_t* gp = (gbl_u32_t*)(unsigned long long)g;
  lds_u32_t* lp = (lds_u32_t*)(unsigned int)(unsigned long long)lds;  // low 32b of generic = LDS offset
  __builtin_amdgcn_global_load_lds(gp, lp, 16, 0, 0);
}

// ---------------- weight pre-transpose + fp32->bf16: W[K,N] -> Bt[N,K] ------
__global__ void prep_weights(const float* __restrict__ Wq, const float* __restrict__ Wk,
                             const float* __restrict__ Wv, const float* __restrict__ Wo,
                             u16* __restrict__ WtQKV, u16* __restrict__ WtO) {
  int idx = blockIdx.x * 256 + threadIdx.x;
  const int QKV_TOT = NLAYER * 3 * EMB * EMB;
  if (idx < QKV_TOT) {
    int l = idx / (3 * EMB * EMB);
    int rem = idx % (3 * EMB * EMB);
    int n = rem / EMB, kk = rem % EMB;
    int w = n >> 9, e = n & 511;
    const float* src = (w == 0) ? Wq : (w == 1) ? Wk : Wv;
    WtQKV[idx] = f2bf(src[((size_t)l * EMB + kk) * EMB + e]);
  } else {
    int j = idx - QKV_TOT;
    int l = j / (EMB * EMB);
    int rem = j % (EMB * EMB);
    int n = rem / EMB, kk = rem % EMB;
    WtO[j] = f2bf(Wo[((size_t)l * EMB + kk) * EMB + n]);
  }
}

// ---------------- embedding + positional encoding (fp32 in, bf16 out) -------
__global__ void embed_pe(const int* __restrict__ inp, const float* __restrict__ table,
                         u16* __restrict__ x) {
  int row = blockIdx.x;
  int tok = inp[row];
  int s = row & (SEQ - 1);
  const float negln = -9.210340371976184f / (float)EMB;
  for (int e = threadIdx.x; e < EMB; e += blockDim.x) {
    float val = table[(size_t)tok * EMB + e];
    int i = e >> 1;
    float dt = expf((float)(2 * i) * negln);
    float ang = (float)s * dt;
    float pe = (e & 1) ? cosf(ang) : sinf(ang);
    x[(size_t)row * EMB + e] = f2bf(val + pe);
  }
}

// ---------------- GEMM: C[M,N] = A[M,K] @ Bt[N,K]^T + bias ------------------
// mode 0: N=1536, scatter Q,K -> [B,H,S,D]; V -> [B,H,D,S] (pre-transposed)
// mode 1: N=512,  x = x + relu(C + bias)   (in place, out0 == resid)
// LDS tiles [128][32] unpadded (global_load_lds needs lane-contiguous dest);
// column-group XOR-swizzle (cg ^= row&3) applied on the lane->global map.
#define BK 32

__global__ __launch_bounds__(256) void gemm_bt(
    const u16* __restrict__ A, const u16* __restrict__ Bt, int K, int mode,
    const float* bias0, const float* bias1, const float* bias2,
    u16* out0, u16* out1, u16* out2, const u16* resid, int Nstride) {
  __shared__ u16 sA[128][BK];
  __shared__ u16 sB[128][BK];
  int tid = threadIdx.x;
  int wave = tid >> 6, lane = tid & 63;
  int quad = lane >> 4, l16 = lane & 15;
  int wm = wave >> 1, wn = wave & 1;
  int bn0 = blockIdx.x * 128, bm0 = blockIdx.y * 128;

  floatx4 acc[4][4];
#pragma unroll
  for (int i = 0; i < 4; ++i)
#pragma unroll
    for (int j = 0; j < 4; ++j) acc[i][j] = (floatx4){0.f, 0.f, 0.f, 0.f};

  int rb = wave * 32;                 // this wave stages rows rb..rb+31 of both tiles
  int lrow = lane >> 2;               // 0..15 row within a 16-row call
  int scg = lane & 3;                 // LDS column-group slot
  int swz = 4 * (scg ^ (lrow & 3)) * 8;  // swizzled global col offset (u16), x4 folded below

  for (int k0 = 0; k0 < K; k0 += BK) {
#pragma unroll
    for (int c = 0; c < 2; ++c) {
      int srow = c * 16 + lrow;
      int gcg = (scg ^ (srow & 3)) * 8;
      gload16(&sA[rb + c * 16][0], &A[(size_t)(bm0 + rb + srow) * K + k0 + gcg]);
      gload16(&sB[rb + c * 16][0], &Bt[(size_t)(bn0 + rb + srow) * K + k0 + gcg]);
    }
    __syncthreads();   // compiler drains vmcnt(0) here
    short8 af[4], bfr[4];
    int rcg = (quad ^ (l16 & 3)) * 8;  // read-side swizzle (row&3 == l16&3)
#pragma unroll
    for (int mi = 0; mi < 4; ++mi)
      af[mi] = *(const short8*)&sA[wm * 64 + mi * 16 + l16][rcg];
#pragma unroll
    for (int ni = 0; ni < 4; ++ni)
      bfr[ni] = *(const short8*)&sB[wn * 64 + ni * 16 + l16][rcg];
#pragma unroll
    for (int mi = 0; mi < 4; ++mi)
#pragma unroll
      for (int ni = 0; ni < 4; ++ni)
        acc[mi][ni] = __builtin_amdgcn_mfma_f32_16x16x32_bf16(af[mi], bfr[ni], acc[mi][ni], 0, 0, 0);
    __syncthreads();
  }
  (void)swz;

#pragma unroll
  for (int mi = 0; mi < 4; ++mi) {
#pragma unroll
    for (int ni = 0; ni < 4; ++ni) {
#pragma unroll
      for (int r = 0; r < 4; ++r) {
        int m = bm0 + wm * 64 + mi * 16 + quad * 4 + r;   // C/D: row = quad*4+reg
        int n = bn0 + wn * 64 + ni * 16 + l16;            // C/D: col = lane&15
        float v = acc[mi][ni][r];
        if (mode == 0) {
          int w = n >> 9, e = n & 511;
          int h = e >> 6, d = e & 63;
          const float* bptr = (w == 0) ? bias0 : (w == 1) ? bias1 : bias2;
          v += bptr[e];
          int b = m >> 10, sid = m & 1023;
          if (w == 2) {  // V pre-transposed: [B,H,D,S]
            out2[((size_t)(b * NH + h) * HD + d) * SEQ + sid] = f2bf(v);
          } else {
            u16* optr = (w == 0) ? out0 : out1;
            optr[((size_t)(b * NH + h) * SEQ + sid) * HD + d] = f2bf(v);
          }
        } else {
          v += bias0[n];
          v = fmaxf(v, 0.f);
          v += bf2f(resid[(size_t)m * Nstride + n]);
          out0[(size_t)m * Nstride + n] = f2bf(v);
        }
      }
    }
  }
}

// ---------------- flash attention, causal, one block per (b*h, qtile) -------
// vt is [B,H,D,S] so the V^T tile stages with clean row-contiguous uint4s.
__global__ __launch_bounds__(256) void attn_kernel(
    const u16* __restrict__ q, const u16* __restrict__ k, const u16* __restrict__ vt,
    u16* __restrict__ o) {
  int bh = blockIdx.x;     // 0..255
  int qt = blockIdx.y;     // 0..15
  int b = bh >> 3, h = bh & 7;
  int q0 = qt * 64;
  __shared__ u16 sQ[64][72], sK[64][72], sV[64][72], sP[64][72];
  int tid = threadIdx.x, wave = tid >> 6, lane = tid & 63;
  int quad = lane >> 4, l16 = lane & 15;

  // stage Q tile [64 q][64 d]
#pragma unroll
  for (int i = 0; i < 2; ++i) {
    int cc = tid + i * 256;
    int row = cc >> 3, cg = cc & 7;
    *(uint4*)&sQ[row][cg * 8] = *(const uint4*)&q[((size_t)bh * SEQ + q0 + row) * HD + cg * 8];
  }

  floatx4 acco[4];
#pragma unroll
  for (int i = 0; i < 4; ++i) acco[i] = (floatx4){0.f, 0.f, 0.f, 0.f};
  float mrow[4], lrow[4];
#pragma unroll
  for (int r = 0; r < 4; ++r) { mrow[r] = -INFINITY; lrow[r] = 0.f; }

  for (int kt = 0; kt <= qt; ++kt) {
    int k0 = kt * 64;
    __syncthreads();   // protect sK/sV reuse (and sQ visibility at kt=0)
#pragma unroll
    for (int i = 0; i < 2; ++i) {
      int cc = tid + i * 256;
      int row = cc >> 3, cg = cc & 7;
      *(uint4*)&sK[row][cg * 8] = *(const uint4*)&k[((size_t)bh * SEQ + k0 + row) * HD + cg * 8];
      *(uint4*)&sV[row][cg * 8] = *(const uint4*)&vt[((size_t)bh * HD + row) * SEQ + k0 + cg * 8];
    }
    __syncthreads();

    // S = Q @ K^T * 1/8 ; wave handles 16 q-rows x 64 keys
    floatx4 accs[4];
#pragma unroll
    for (int i = 0; i < 4; ++i) accs[i] = (floatx4){0.f, 0.f, 0.f, 0.f};
#pragma unroll
    for (int cst = 0; cst < 2; ++cst) {
      short8 aq = *(const short8*)&sQ[wave * 16 + l16][cst * 32 + quad * 8];
#pragma unroll
      for (int nt = 0; nt < 4; ++nt) {
        short8 bk_ = *(const short8*)&sK[nt * 16 + l16][cst * 32 + quad * 8];
        accs[nt] = __builtin_amdgcn_mfma_f32_16x16x32_bf16(aq, bk_, accs[nt], 0, 0, 0);
      }
    }

    // online softmax; only the diagonal tile needs masking
    bool diag = (kt == qt);
    int qg_base = q0 + wave * 16 + quad * 4;
    float pvv[4][4];
#pragma unroll
    for (int r = 0; r < 4; ++r) {
      float mx = -INFINITY;
#pragma unroll
      for (int nt = 0; nt < 4; ++nt) {
        float s = accs[nt][r] * 0.125f;
        if (diag) {
          int kg = k0 + nt * 16 + l16;
          if (kg > qg_base + r) s = -INFINITY;
        }
        pvv[nt][r] = s;
        mx = fmaxf(mx, s);
      }
#pragma unroll
      for (int sh = 1; sh < 16; sh <<= 1) mx = fmaxf(mx, __shfl_xor(mx, sh, 64));
      float mn = fmaxf(mrow[r], mx);
      float alpha = __expf(mrow[r] - mn);
      float sum = 0.f;
#pragma unroll
      for (int nt = 0; nt < 4; ++nt) {
        float p = __expf(pvv[nt][r] - mn);
        pvv[nt][r] = p;
        sum += p;
      }
#pragma unroll
      for (int sh = 1; sh < 16; sh <<= 1) sum += __shfl_xor(sum, sh, 64);
      lrow[r] = lrow[r] * alpha + sum;
      mrow[r] = mn;
#pragma unroll
      for (int dt = 0; dt < 4; ++dt) acco[dt][r] *= alpha;
    }

    // P (C-layout) -> LDS -> A-layout. Wave-private rows: no barrier needed,
    // just drain DS ops so other lanes' writes are visible.
#pragma unroll
    for (int nt = 0; nt < 4; ++nt)
#pragma unroll
      for (int r = 0; r < 4; ++r)
        sP[wave * 16 + quad * 4 + r][nt * 16 + l16] =
            (u16)(__float_as_uint(pvv[nt][r]) >> 16);   // truncate: P in [0,1]
    asm volatile("s_waitcnt lgkmcnt(0)" ::: "memory");

#pragma unroll
    for (int cst = 0; cst < 2; ++cst) {
      short8 ap = *(const short8*)&sP[wave * 16 + l16][cst * 32 + quad * 8];
#pragma unroll
      for (int dt = 0; dt < 4; ++dt) {
        short8 bv_ = *(const short8*)&sV[dt * 16 + l16][cst * 32 + quad * 8];
        acco[dt] = __builtin_amdgcn_mfma_f32_16x16x32_bf16(ap, bv_, acco[dt], 0, 0, 0);
      }
    }
  }

  // normalize + write [B,S,E]
#pragma unroll
  for (int dt = 0; dt < 4; ++dt)
#pragma unroll
    for (int r = 0; r < 4; ++r) {
      float ov = acco[dt][r] / lrow[r];
      int srow = q0 + wave * 16 + quad * 4 + r;
      int col = h * HD + dt * 16 + l16;
      o[((size_t)b * SEQ + srow) * EMB + col] = f2bf(ov);
    }
}

// ---------------- output head: out[m] = x[m,:] . W_out + b_out (fp32 out) ---
__global__ __launch_bounds__(256) void out_proj(const u16* __restrict__ x,
                                                const float* __restrict__ wout,
                                                const float* __restrict__ bout,
                                                float* __restrict__ out) {
  int wave = threadIdx.x >> 6, lane = threadIdx.x & 63;
  int m = blockIdx.x * 4 + wave;
  union { uint4 vv; u16 s[8]; } xv;
  xv.vv = *(const uint4*)&x[(size_t)m * EMB + lane * 8];
  float4 w0 = *(const float4*)&wout[lane * 8];
  float4 w1 = *(const float4*)&wout[lane * 8 + 4];
  float wv[8] = {w0.x, w0.y, w0.z, w0.w, w1.x, w1.y, w1.z, w1.w};
  float s = 0.f;
#pragma unroll
  for (int j = 0; j < 8; ++j) s += bf2f(xv.s[j]) * wv[j];
#pragma unroll
  for (int sh = 1; sh < 64; sh <<= 1) s += __shfl_xor(s, sh, 64);
  if (lane == 0) out[m] = s + bout[0];
}

extern "C" void kernel_launch(void* const* d_in, const int* in_sizes, int n_in,
                              void* d_out, int out_size, void* d_ws, size_t ws_size,
                              hipStream_t stream) {
  const int*   inp   = (const int*)d_in[0];
  const float* table = (const float*)d_in[1];
  const float* Wq    = (const float*)d_in[2];
  const float* bq    = (const float*)d_in[3];
  const float* Wk    = (const float*)d_in[4];
  const float* bk    = (const float*)d_in[5];
  const float* Wv    = (const float*)d_in[6];
  const float* bv    = (const float*)d_in[7];
  const float* Wo    = (const float*)d_in[8];
  const float* bo    = (const float*)d_in[9];
  const float* Wout  = (const float*)d_in[10];
  const float* bout  = (const float*)d_in[11];
  float* outp = (float*)d_out;

  char* ws = (char*)d_ws;
  const size_t SZ = (size_t)M_ROWS * EMB * 2;  // 32 MB
  u16* x      = (u16*)(ws);
  u16* qb     = (u16*)(ws + SZ);
  u16* kb     = (u16*)(ws + 2 * SZ);
  u16* vb     = (u16*)(ws + 3 * SZ);   // [B,H,D,S]
  u16* attn_b = (u16*)(ws + 4 * SZ);
  u16* WtQKV  = (u16*)(ws + 5 * SZ);
  u16* WtO    = (u16*)(ws + 5 * SZ + (size_t)NLAYER * 3 * EMB * EMB * 2);

  prep_weights<<<8192, 256, 0, stream>>>(Wq, Wk, Wv, Wo, WtQKV, WtO);
  embed_pe<<<M_ROWS, 256, 0, stream>>>(inp, table, x);

  for (int l = 0; l < NLAYER; ++l) {
    gemm_bt<<<dim3(12, 256), 256, 0, stream>>>(
        x, WtQKV + (size_t)l * 3 * EMB * EMB, EMB, /*mode=*/0,
        bq + l * EMB, bk + l * EMB, bv + l * EMB, qb, kb, vb, nullptr, 0);
    attn_kernel<<<dim3(256, 16), 256, 0, stream>>>(qb, kb, vb, attn_b);
    gemm_bt<<<dim3(4, 256), 256, 0, stream>>>(
        attn_b, WtO + (size_t)l * EMB * EMB, EMB, /*mode=*/1,
        bo + l * EMB, nullptr, nullptr, x, nullptr, nullptr, x, EMB);
  }
  out_proj<<<8192, 256, 0, stream>>>(x, Wout, bout, outp);
}